// Round 6
// baseline (210.758 us; speedup 1.0000x reference)
//
#include <hip/hip_runtime.h>

#define H 16
#define N 2048
#define E 64
#define D 1024

typedef __attribute__((ext_vector_type(8))) short bf16x8;
typedef __attribute__((ext_vector_type(4))) float f32x4;

__device__ __forceinline__ float bf2f(unsigned short u) {
    union { unsigned int i; float f; } v;
    v.i = ((unsigned int)u) << 16;
    return v.f;
}
__device__ __forceinline__ unsigned short f2bf(float f) {
    unsigned int u = __float_as_uint(f);
    return (unsigned short)((u + 0x7fffu + ((u >> 16) & 1u)) >> 16);
}
#define MFMA(a, b, c) __builtin_amdgcn_mfma_f32_16x16x32_bf16(a, b, c, 0, 0, 0)

// async global->LDS, 16B per lane. LDS dest must be base+lane*16 contiguous.
typedef __attribute__((address_space(3))) unsigned int lds_u32;
typedef const __attribute__((address_space(1))) unsigned int glb_u32;
__device__ __forceinline__ void dma16(const unsigned short* g, unsigned short* l) {
    __builtin_amdgcn_global_load_lds((glb_u32*)g, (lds_u32*)l, 16, 0, 0);
}

// XOR-swizzled LDS tiles (16B chunk granularity): physical chunk = c ^ (row&7).
__device__ __forceinline__ int sw8(int row, int c)  { return row * 64  + ((c ^ (row & 7)) << 3); }
__device__ __forceinline__ int sw16(int row, int c) { return row * 128 + ((c ^ (row & 7)) << 3); }

// ---------------------------------------------------------------------------
// K1: x fp32 -> xh/xl bf16 hi/lo, same [n][d] layout.
// ---------------------------------------------------------------------------
__global__ __launch_bounds__(256) void convert_x_kernel(
    const float* __restrict__ x, unsigned short* __restrict__ xh,
    unsigned short* __restrict__ xl)
{
    const int i = (blockIdx.x * 256 + threadIdx.x) * 4;
    const float4 v = *(const float4*)&x[i];
    ushort4 hh, ll;
    hh.x = f2bf(v.x); ll.x = f2bf(v.x - bf2f(hh.x));
    hh.y = f2bf(v.y); ll.y = f2bf(v.y - bf2f(hh.y));
    hh.z = f2bf(v.z); ll.z = f2bf(v.z - bf2f(hh.z));
    hh.w = f2bf(v.w); ll.w = f2bf(v.w - bf2f(hh.w));
    *(ushort4*)&xh[i] = hh;
    *(ushort4*)&xl[i] = ll;
}

// ---------------------------------------------------------------------------
// K2: transpose-convert weights (known-good).
// ---------------------------------------------------------------------------
__global__ __launch_bounds__(256) void convert_w_kernel(
    const float* __restrict__ qw, const float* __restrict__ kw,
    const float* __restrict__ vw, const float* __restrict__ ow,
    unsigned short* __restrict__ wBh, unsigned short* __restrict__ wBl,
    unsigned short* __restrict__ wvt,
    unsigned short* __restrict__ woh, unsigned short* __restrict__ wol)
{
    __shared__ float ts[64][65];
    const int b = blockIdx.x;
    const int t = threadIdx.x;
    const float* src;
    int rs, dt, orow0;
    bool has_lo;
    unsigned short *dh, *dl;
    if (b < 768) {
        const int which = b >> 8, r = b & 255, h = r >> 4;
        dt = r & 15;
        src = (which == 0 ? qw : which == 1 ? kw : vw) + ((size_t)h * D + dt * 64) * E;
        rs = E;
        if (which == 0)      { dh = wBh; dl = wBl; orow0 = h * 64;        has_lo = true; }
        else if (which == 1) { dh = wBh; dl = wBl; orow0 = 1024 + h * 64; has_lo = true; }
        else                 { dh = wvt; dl = wBl; orow0 = h * 64;        has_lo = false; }
    } else {
        const int r = b - 768, ct = r >> 4;
        dt = r & 15;
        src = ow + (size_t)(dt * 64) * D + ct * 64;
        rs = D;
        orow0 = ct * 64;
        dh = woh; dl = wol; has_lo = true;
    }
    {
        const int row = t >> 2, cb = (t & 3) * 16;
        #pragma unroll
        for (int j = 0; j < 16; j += 4) {
            const float4 v = *(const float4*)&src[row * rs + cb + j];
            ts[row][cb + j + 0] = v.x;
            ts[row][cb + j + 1] = v.y;
            ts[row][cb + j + 2] = v.z;
            ts[row][cb + j + 3] = v.w;
        }
    }
    __syncthreads();
    {
        const int cl = t >> 2, dp = (t & 3) * 16;
        bf16x8 hv0, hv1, lv0, lv1;
        #pragma unroll
        for (int i = 0; i < 16; ++i) {
            const float f = ts[dp + i][cl];
            const unsigned short hh = f2bf(f);
            const unsigned short lo = f2bf(f - bf2f(hh));
            if (i < 8) { hv0[i] = (short)hh; lv0[i] = (short)lo; }
            else       { hv1[i - 8] = (short)hh; lv1[i - 8] = (short)lo; }
        }
        const size_t o = (size_t)(orow0 + cl) * D + dt * 64 + dp;
        *(bf16x8*)&dh[o] = hv0;
        *(bf16x8*)&dh[o + 8] = hv1;
        if (has_lo) {
            *(bf16x8*)&dl[o] = lv0;
            *(bf16x8*)&dl[o + 8] = lv1;
        }
    }
}

// ---------------------------------------------------------------------------
// K3: QKV projection, 128x128 tiles, BK=64, DMA-staged. grid (16, 24).
// by in [0,8): Q cols; [8,16): K cols; [16,24): V cols (2 heads per tile).
// Q/K 3-term split; V 1-term.
// ---------------------------------------------------------------------------
__global__ __launch_bounds__(256, 2) void qkv_kernel(
    const unsigned short* __restrict__ xh, const unsigned short* __restrict__ xl,
    const unsigned short* __restrict__ wBh, const unsigned short* __restrict__ wBl,
    const unsigned short* __restrict__ wvt,
    unsigned short* __restrict__ Qh, unsigned short* __restrict__ Ql,
    unsigned short* __restrict__ Kh, unsigned short* __restrict__ Kl,
    unsigned short* __restrict__ Vt)
{
    __shared__ unsigned short ash[128 * 64], asl[128 * 64];
    __shared__ unsigned short bsh[128 * 64], bsl[128 * 64];
    const int n0 = blockIdx.x * 128;
    const int by = blockIdx.y;
    const bool isv = (by >= 16);
    const unsigned short* Bh = isv ? wvt : wBh;
    const size_t brow0 = isv ? (size_t)(by - 16) * 128 : (size_t)by * 128;

    const int t = threadIdx.x;
    const int lane = t & 63, wvi = t >> 6, quad = lane >> 4, l15 = lane & 15;
    const int qr = (wvi >> 1) * 64, qc = (wvi & 1) * 64;

    f32x4 acc[4][4];
    #pragma unroll
    for (int i = 0; i < 4; ++i)
        #pragma unroll
        for (int j = 0; j < 4; ++j) acc[i][j] = (f32x4){0.f, 0.f, 0.f, 0.f};

    for (int k0 = 0; k0 < D; k0 += 64) {
        __syncthreads();
        #pragma unroll
        for (int p = 0; p < 4; ++p) {
            const int row = p * 32 + wvi * 8 + (lane >> 3);
            const int lc = (lane & 7) ^ (row & 7);
            const int lo = p * 2048 + wvi * 512 + lane * 8;
            const size_t ga = (size_t)(n0 + row) * D + k0 + lc * 8;
            const size_t gb = (brow0 + row) * D + k0 + lc * 8;
            dma16(&xh[ga], &ash[lo]);
            dma16(&Bh[gb], &bsh[lo]);
            if (!isv) {
                dma16(&xl[ga], &asl[lo]);
                dma16(&wBl[gb], &bsl[lo]);
            }
        }
        __syncthreads();

        #pragma unroll
        for (int kwi = 0; kwi < 2; ++kwi) {
            const int c = kwi * 4 + quad;
            bf16x8 ah[4], al[4], bh[4], bl[4];
            #pragma unroll
            for (int i = 0; i < 4; ++i) {
                ah[i] = *(const bf16x8*)&ash[sw8(qr + i * 16 + l15, c)];
                bh[i] = *(const bf16x8*)&bsh[sw8(qc + i * 16 + l15, c)];
                if (!isv) {
                    al[i] = *(const bf16x8*)&asl[sw8(qr + i * 16 + l15, c)];
                    bl[i] = *(const bf16x8*)&bsl[sw8(qc + i * 16 + l15, c)];
                }
            }
            #pragma unroll
            for (int i = 0; i < 4; ++i)
                #pragma unroll
                for (int j = 0; j < 4; ++j) {
                    acc[i][j] = MFMA(ah[i], bh[j], acc[i][j]);
                    if (!isv) {
                        acc[i][j] = MFMA(ah[i], bl[j], acc[i][j]);
                        acc[i][j] = MFMA(al[i], bh[j], acc[i][j]);
                    }
                }
        }
    }

    if (isv) {
        #pragma unroll
        for (int j = 0; j < 4; ++j) {
            const int vcol = (by - 16) * 128 + qc + j * 16 + l15;   // = h*64+e
            #pragma unroll
            for (int i = 0; i < 4; ++i) {
                const int nb = n0 + qr + i * 16 + quad * 4;
                ushort4 pk;
                pk.x = f2bf(acc[i][j][0]);
                pk.y = f2bf(acc[i][j][1]);
                pk.z = f2bf(acc[i][j][2]);
                pk.w = f2bf(acc[i][j][3]);
                *(ushort4*)&Vt[(size_t)vcol * N + nb] = pk;
            }
        }
    } else {
        const bool isq = (by < 8);
        const float scale = isq ? 0.125f : 1.0f;   // fold 1/sqrt(64) into Q
        unsigned short* Oh = isq ? Qh : Kh;
        unsigned short* Ol = isq ? Ql : Kl;
        #pragma unroll
        for (int j = 0; j < 4; ++j) {
            const int fcol = (by & 7) * 128 + qc + j * 16 + l15;    // 0..1023
            const int hh = fcol >> 6, e = fcol & 63;
            #pragma unroll
            for (int i = 0; i < 4; ++i)
                #pragma unroll
                for (int r = 0; r < 4; ++r) {
                    const int n = n0 + qr + i * 16 + quad * 4 + r;
                    const float val = acc[i][j][r] * scale;
                    const unsigned short hv = f2bf(val);
                    Oh[((size_t)hh * N + n) * E + e] = hv;
                    Ol[((size_t)hh * N + n) * E + e] = f2bf(val - bf2f(hv));
                }
        }
    }
}

// ---------------------------------------------------------------------------
// K4: flash attention (unchanged from R5 — control). grid (32, 16).
// ---------------------------------------------------------------------------
__global__ __launch_bounds__(256, 2) void attn_kernel(
    const unsigned short* __restrict__ Qh, const unsigned short* __restrict__ Ql,
    const unsigned short* __restrict__ Kh, const unsigned short* __restrict__ Kl,
    const unsigned short* __restrict__ Vt,
    unsigned short* __restrict__ Ch, unsigned short* __restrict__ Cl)
{
    __shared__ unsigned short ksh[128 * 64], ksl[128 * 64];
    __shared__ unsigned short vts[64 * 128];
    __shared__ unsigned short ps[4 * 16 * 136];
    const int r0 = blockIdx.x * 64, h = blockIdx.y;
    const int t = threadIdx.x, lane = t & 63, wvi = t >> 6, quad = lane >> 4, l15 = lane & 15;

    bf16x8 qfh[2], qfl[2];
    {
        const size_t base = ((size_t)h * N + r0 + wvi * 16 + l15) * E;
        #pragma unroll
        for (int kwi = 0; kwi < 2; ++kwi) {
            qfh[kwi] = *(const bf16x8*)&Qh[base + kwi * 32 + quad * 8];
            qfl[kwi] = *(const bf16x8*)&Ql[base + kwi * 32 + quad * 8];
        }
    }

    f32x4 oacc[4];
    #pragma unroll
    for (int ct = 0; ct < 4; ++ct) oacc[ct] = (f32x4){0.f, 0.f, 0.f, 0.f};
    float mrow[4] = {-1e30f, -1e30f, -1e30f, -1e30f};
    float lrow[4] = {0.f, 0.f, 0.f, 0.f};

    for (int m0 = 0; m0 < N; m0 += 128) {
        __syncthreads();
        #pragma unroll
        for (int p = 0; p < 4; ++p) {
            const int row = p * 32 + wvi * 8 + (lane >> 3);
            const int lc = (lane & 7) ^ (row & 7);
            const int lo = p * 2048 + wvi * 512 + lane * 8;
            const size_t gk = ((size_t)h * N + m0 + row) * E + lc * 8;
            dma16(&Kh[gk], &ksh[lo]);
            dma16(&Kl[gk], &ksl[lo]);
        }
        #pragma unroll
        for (int p = 0; p < 4; ++p) {
            const int row = p * 16 + wvi * 4 + (lane >> 4);
            const int lc = (lane & 15) ^ (row & 7);
            const int lo = p * 2048 + wvi * 512 + lane * 8;
            dma16(&Vt[((size_t)h * 64 + row) * N + m0 + lc * 8], &vts[lo]);
        }
        __syncthreads();

        f32x4 s[8];
        #pragma unroll
        for (int ct = 0; ct < 8; ++ct) s[ct] = (f32x4){0.f, 0.f, 0.f, 0.f};
        #pragma unroll
        for (int kwi = 0; kwi < 2; ++kwi) {
            const int c = kwi * 4 + quad;
            #pragma unroll
            for (int ct = 0; ct < 8; ++ct) {
                const bf16x8 bh = *(const bf16x8*)&ksh[sw8(ct * 16 + l15, c)];
                const bf16x8 bl = *(const bf16x8*)&ksl[sw8(ct * 16 + l15, c)];
                s[ct] = MFMA(qfh[kwi], bh, s[ct]);
                s[ct] = MFMA(qfh[kwi], bl, s[ct]);
                s[ct] = MFMA(qfl[kwi], bh, s[ct]);
            }
        }

        #pragma unroll
        for (int r = 0; r < 4; ++r) {
            float mx = s[0][r];
            #pragma unroll
            for (int ct = 1; ct < 8; ++ct) mx = fmaxf(mx, s[ct][r]);
            mx = fmaxf(mx, __shfl_xor(mx, 1));
            mx = fmaxf(mx, __shfl_xor(mx, 2));
            mx = fmaxf(mx, __shfl_xor(mx, 4));
            mx = fmaxf(mx, __shfl_xor(mx, 8));
            const float mn = fmaxf(mrow[r], mx);
            const float alpha = __expf(mrow[r] - mn);
            mrow[r] = mn;
            float sum = 0.f;
            #pragma unroll
            for (int ct = 0; ct < 8; ++ct) {
                const float p = __expf(s[ct][r] - mn);
                s[ct][r] = p;
                sum += p;
            }
            sum += __shfl_xor(sum, 1);
            sum += __shfl_xor(sum, 2);
            sum += __shfl_xor(sum, 4);
            sum += __shfl_xor(sum, 8);
            lrow[r] = lrow[r] * alpha + sum;
            #pragma unroll
            for (int ct = 0; ct < 4; ++ct) oacc[ct][r] *= alpha;
        }

        #pragma unroll
        for (int ct = 0; ct < 8; ++ct)
            #pragma unroll
            for (int r = 0; r < 4; ++r)
                ps[(wvi * 16 + quad * 4 + r) * 136 + ct * 16 + l15] = f2bf(s[ct][r]);

        #pragma unroll
        for (int kwi = 0; kwi < 4; ++kwi) {
            const bf16x8 pa = *(const bf16x8*)&ps[(wvi * 16 + l15) * 136 + kwi * 32 + quad * 8];
            #pragma unroll
            for (int ct = 0; ct < 4; ++ct) {
                const bf16x8 vb = *(const bf16x8*)&vts[sw16(ct * 16 + l15, kwi * 4 + quad)];
                oacc[ct] = MFMA(pa, vb, oacc[ct]);
            }
        }
    }

    #pragma unroll
    for (int r = 0; r < 4; ++r) {
        const float inv = 1.f / lrow[r];
        const int n = r0 + wvi * 16 + quad * 4 + r;
        #pragma unroll
        for (int ct = 0; ct < 4; ++ct) {
            const int c = h * 64 + ct * 16 + l15;
            const float val = oacc[ct][r] * inv;
            const unsigned short hv = f2bf(val);
            Ch[(size_t)n * D + c] = hv;
            Cl[(size_t)n * D + c] = f2bf(val - bf2f(hv));
        }
    }
}

// ---------------------------------------------------------------------------
// K5: out = ctx @ Wo, 128x128 tiles, split-K=2, atomicAdd epilogue.
// grid (16, 8, 2); out must be zeroed before launch.
// ---------------------------------------------------------------------------
__global__ __launch_bounds__(256, 2) void out_proj_kernel(
    const unsigned short* __restrict__ Chh, const unsigned short* __restrict__ Cll,
    const unsigned short* __restrict__ Wh, const unsigned short* __restrict__ Wl,
    float* __restrict__ out)
{
    __shared__ unsigned short ash[128 * 64], asl[128 * 64];
    __shared__ unsigned short bsh[128 * 64], bsl[128 * 64];
    const int n0 = blockIdx.x * 128, c0 = blockIdx.y * 128;
    const int kbase = blockIdx.z * 512;
    const int t = threadIdx.x, lane = t & 63, wvi = t >> 6, quad = lane >> 4, l15 = lane & 15;
    const int qr = (wvi >> 1) * 64, qc = (wvi & 1) * 64;

    f32x4 acc[4][4];
    #pragma unroll
    for (int i = 0; i < 4; ++i)
        #pragma unroll
        for (int j = 0; j < 4; ++j) acc[i][j] = (f32x4){0.f, 0.f, 0.f, 0.f};

    for (int k0 = kbase; k0 < kbase + 512; k0 += 64) {
        __syncthreads();
        #pragma unroll
        for (int p = 0; p < 4; ++p) {
            const int row = p * 32 + wvi * 8 + (lane >> 3);
            const int lc = (lane & 7) ^ (row & 7);
            const int lo = p * 2048 + wvi * 512 + lane * 8;
            const size_t ga = (size_t)(n0 + row) * D + k0 + lc * 8;
            const size_t gb = (size_t)(c0 + row) * D + k0 + lc * 8;
            dma16(&Chh[ga], &ash[lo]);
            dma16(&Cll[ga], &asl[lo]);
            dma16(&Wh[gb], &bsh[lo]);
            dma16(&Wl[gb], &bsl[lo]);
        }
        __syncthreads();

        #pragma unroll
        for (int kwi = 0; kwi < 2; ++kwi) {
            const int c = kwi * 4 + quad;
            bf16x8 ah[4], al[4], bh[4], bl[4];
            #pragma unroll
            for (int i = 0; i < 4; ++i) {
                ah[i] = *(const bf16x8*)&ash[sw8(qr + i * 16 + l15, c)];
                al[i] = *(const bf16x8*)&asl[sw8(qr + i * 16 + l15, c)];
                bh[i] = *(const bf16x8*)&bsh[sw8(qc + i * 16 + l15, c)];
                bl[i] = *(const bf16x8*)&bsl[sw8(qc + i * 16 + l15, c)];
            }
            #pragma unroll
            for (int i = 0; i < 4; ++i)
                #pragma unroll
                for (int j = 0; j < 4; ++j) {
                    acc[i][j] = MFMA(ah[i], bh[j], acc[i][j]);
                    acc[i][j] = MFMA(ah[i], bl[j], acc[i][j]);
                    acc[i][j] = MFMA(al[i], bh[j], acc[i][j]);
                }
        }
    }

    #pragma unroll
    for (int i = 0; i < 4; ++i)
        #pragma unroll
        for (int r = 0; r < 4; ++r) {
            const int n = n0 + qr + i * 16 + quad * 4 + r;
            #pragma unroll
            for (int j = 0; j < 4; ++j)
                atomicAdd(&out[(size_t)n * D + c0 + qc + j * 16 + l15], acc[i][j][r]);
        }
}

// ---------------------------------------------------------------------------
extern "C" void kernel_launch(void* const* d_in, const int* in_sizes, int n_in,
                              void* d_out, int out_size, void* d_ws, size_t ws_size,
                              hipStream_t stream) {
    const float* x  = (const float*)d_in[0];
    const float* qw = (const float*)d_in[1];
    const float* kw = (const float*)d_in[2];
    const float* vw = (const float*)d_in[3];
    const float* ow = (const float*)d_in[4];
    float* out = (float*)d_out;

    unsigned short* ws = (unsigned short*)d_ws;
    const size_t M1 = 1024 * 1024;
    unsigned short* wBh = ws;                 // [2048][1024] = 2M shorts
    unsigned short* wBl = ws + 2 * M1;
    unsigned short* wvt = ws + 4 * M1;        // [1024][1024] = 1M
    unsigned short* woh = ws + 5 * M1;
    unsigned short* wol = ws + 6 * M1;
    unsigned short* xh  = ws + 7 * M1;        // [2048][1024] = 2M
    unsigned short* xl  = ws + 9 * M1;
    unsigned short* Qh  = ws + 11 * M1;       // [h][n][e] = 2M
    unsigned short* Ql  = ws + 13 * M1;
    unsigned short* Kh  = ws + 15 * M1;
    unsigned short* Kl  = ws + 17 * M1;
    unsigned short* Vt  = ws + 19 * M1;       // [h*64+e][n] = 2M
    unsigned short* Ch  = xh;                 // alias: x dead after qkv
    unsigned short* Cl  = xl;

    hipMemsetAsync(out, 0, (size_t)out_size * sizeof(float), stream);
    convert_x_kernel<<<(N * D / 4) / 256, 256, 0, stream>>>(x, xh, xl);
    convert_w_kernel<<<1024, 256, 0, stream>>>(qw, kw, vw, ow, wBh, wBl, wvt, woh, wol);
    qkv_kernel<<<dim3(16, 24), 256, 0, stream>>>(xh, xl, wBh, wBl, wvt, Qh, Ql, Kh, Kl, Vt);
    attn_kernel<<<dim3(32, 16), 256, 0, stream>>>(Qh, Ql, Kh, Kl, Vt, Ch, Cl);
    out_proj_kernel<<<dim3(16, 8, 2), 256, 0, stream>>>(Ch, Cl, woh, wol, out);
}

// Round 7
// 181.140 us; speedup vs baseline: 1.1635x; 1.1635x over previous
//
#include <hip/hip_runtime.h>

#define H 16
#define N 2048
#define E 64
#define D 1024

typedef __attribute__((ext_vector_type(8))) short bf16x8;
typedef __attribute__((ext_vector_type(4))) float f32x4;

__device__ __forceinline__ float bf2f(unsigned short u) {
    union { unsigned int i; float f; } v;
    v.i = ((unsigned int)u) << 16;
    return v.f;
}
__device__ __forceinline__ unsigned short f2bf(float f) {
    unsigned int u = __float_as_uint(f);
    return (unsigned short)((u + 0x7fffu + ((u >> 16) & 1u)) >> 16);
}
#define MFMA(a, b, c) __builtin_amdgcn_mfma_f32_16x16x32_bf16(a, b, c, 0, 0, 0)

// async global->LDS, 16B per lane. LDS dest must be base+lane*16 contiguous.
typedef __attribute__((address_space(3))) unsigned int lds_u32;
typedef const __attribute__((address_space(1))) unsigned int glb_u32;
__device__ __forceinline__ void dma16(const unsigned short* g, unsigned short* l) {
    __builtin_amdgcn_global_load_lds((glb_u32*)g, (lds_u32*)l, 16, 0, 0);
}

// XOR-swizzled LDS tiles (16B chunk granularity): physical chunk = c ^ (row&7).
__device__ __forceinline__ int sw8(int row, int c)  { return row * 64  + ((c ^ (row & 7)) << 3); }
__device__ __forceinline__ int sw16(int row, int c) { return row * 128 + ((c ^ (row & 7)) << 3); }

// ---------------------------------------------------------------------------
// K1: merged converts. blocks [0,2048): x fp32 -> xh/xl.
// blocks [2048,3072): weights. q -> wBh/wBl rows [0,1024); k -> rows
// [1024,2048); v -> wvt [h*64+e][d] (hi only); o -> woh [c][d] (hi only).
// ---------------------------------------------------------------------------
__global__ __launch_bounds__(256) void convert_all_kernel(
    const float* __restrict__ x,
    const float* __restrict__ qw, const float* __restrict__ kw,
    const float* __restrict__ vw, const float* __restrict__ ow,
    unsigned short* __restrict__ xh, unsigned short* __restrict__ xl,
    unsigned short* __restrict__ wBh, unsigned short* __restrict__ wBl,
    unsigned short* __restrict__ wvt, unsigned short* __restrict__ woh)
{
    __shared__ float ts[64][65];
    const int b0 = blockIdx.x;
    const int t = threadIdx.x;
    if (b0 < 2048) {
        const int i = (b0 * 256 + t) * 4;
        const float4 v = *(const float4*)&x[i];
        ushort4 hh, ll;
        hh.x = f2bf(v.x); ll.x = f2bf(v.x - bf2f(hh.x));
        hh.y = f2bf(v.y); ll.y = f2bf(v.y - bf2f(hh.y));
        hh.z = f2bf(v.z); ll.z = f2bf(v.z - bf2f(hh.z));
        hh.w = f2bf(v.w); ll.w = f2bf(v.w - bf2f(hh.w));
        *(ushort4*)&xh[i] = hh;
        *(ushort4*)&xl[i] = ll;
        return;
    }
    const int b = b0 - 2048;
    const float* src;
    int rs, dt, orow0;
    bool has_lo;
    unsigned short *dh, *dl;
    if (b < 768) {
        const int which = b >> 8, r = b & 255, h = r >> 4;
        dt = r & 15;
        src = (which == 0 ? qw : which == 1 ? kw : vw) + ((size_t)h * D + dt * 64) * E;
        rs = E;
        if (which == 0)      { dh = wBh; dl = wBl; orow0 = h * 64;        has_lo = true; }
        else if (which == 1) { dh = wBh; dl = wBl; orow0 = 1024 + h * 64; has_lo = true; }
        else                 { dh = wvt; dl = wBl; orow0 = h * 64;        has_lo = false; }
    } else {
        const int r = b - 768, ct = r >> 4;
        dt = r & 15;
        src = ow + (size_t)(dt * 64) * D + ct * 64;
        rs = D;
        orow0 = ct * 64;
        dh = woh; dl = wBl; has_lo = false;   // o: hi only
    }
    {
        const int row = t >> 2, cb = (t & 3) * 16;
        #pragma unroll
        for (int j = 0; j < 16; j += 4) {
            const float4 v = *(const float4*)&src[row * rs + cb + j];
            ts[row][cb + j + 0] = v.x;
            ts[row][cb + j + 1] = v.y;
            ts[row][cb + j + 2] = v.z;
            ts[row][cb + j + 3] = v.w;
        }
    }
    __syncthreads();
    {
        const int cl = t >> 2, dp = (t & 3) * 16;
        bf16x8 hv0, hv1, lv0, lv1;
        #pragma unroll
        for (int i = 0; i < 16; ++i) {
            const float f = ts[dp + i][cl];
            const unsigned short hh = f2bf(f);
            const unsigned short lo = f2bf(f - bf2f(hh));
            if (i < 8) { hv0[i] = (short)hh; lv0[i] = (short)lo; }
            else       { hv1[i - 8] = (short)hh; lv1[i - 8] = (short)lo; }
        }
        const size_t o = (size_t)(orow0 + cl) * D + dt * 64 + dp;
        *(bf16x8*)&dh[o] = hv0;
        *(bf16x8*)&dh[o + 8] = hv1;
        if (has_lo) {
            *(bf16x8*)&dl[o] = lv0;
            *(bf16x8*)&dl[o + 8] = lv1;
        }
    }
}

// ---------------------------------------------------------------------------
// K2: QKV projection (R5-exact config). grid (16 Mtiles, 48 col-tiles).
// Tile 128 rows x 64 cols, BK=64, DMA-staged. [0,16)=Q, [16,32)=K, [32,48)=V.
// ---------------------------------------------------------------------------
__global__ __launch_bounds__(256, 3) void qkv_kernel(
    const unsigned short* __restrict__ xh, const unsigned short* __restrict__ xl,
    const unsigned short* __restrict__ wBh, const unsigned short* __restrict__ wBl,
    const unsigned short* __restrict__ wvt,
    unsigned short* __restrict__ Qh, unsigned short* __restrict__ Ql,
    unsigned short* __restrict__ Kh, unsigned short* __restrict__ Kl,
    unsigned short* __restrict__ Vt)
{
    __shared__ unsigned short ash[128 * 64], asl[128 * 64];
    __shared__ unsigned short bsh[64 * 64], bsl[64 * 64];
    const int n0 = blockIdx.x * 128;
    const int ct0 = blockIdx.y;
    const int sec = ct0 >> 4;            // 0=Q 1=K 2=V
    const int hh = ct0 & 15;
    const bool isv = (sec == 2);
    const unsigned short* Bh = isv ? wvt : wBh;
    const size_t brow0 = (sec == 1 ? 1024 : 0) + hh * 64;

    const int t = threadIdx.x;
    const int lane = t & 63, wvi = t >> 6, quad = lane >> 4, l15 = lane & 15;

    f32x4 acc[2][4];
    #pragma unroll
    for (int i = 0; i < 2; ++i)
        #pragma unroll
        for (int j = 0; j < 4; ++j) acc[i][j] = (f32x4){0.f, 0.f, 0.f, 0.f};

    for (int k0 = 0; k0 < D; k0 += 64) {
        __syncthreads();
        #pragma unroll
        for (int p = 0; p < 4; ++p) {
            const int row = p * 32 + wvi * 8 + (lane >> 3);
            const int lc = (lane & 7) ^ (row & 7);
            const int lo = p * 2048 + wvi * 512 + lane * 8;
            const size_t ga = (size_t)(n0 + row) * D + k0 + lc * 8;
            dma16(&xh[ga], &ash[lo]);
            if (!isv) dma16(&xl[ga], &asl[lo]);
        }
        #pragma unroll
        for (int p = 0; p < 2; ++p) {
            const int row = p * 32 + wvi * 8 + (lane >> 3);
            const int lc = (lane & 7) ^ (row & 7);
            const int lo = p * 2048 + wvi * 512 + lane * 8;
            const size_t gb = (brow0 + row) * D + k0 + lc * 8;
            dma16(&Bh[gb], &bsh[lo]);
            if (!isv) dma16(&wBl[gb], &bsl[lo]);
        }
        __syncthreads();

        #pragma unroll
        for (int kwi = 0; kwi < 2; ++kwi) {
            const int c = kwi * 4 + quad;
            bf16x8 ah[2], al[2], bh[4], bl[4];
            #pragma unroll
            for (int i = 0; i < 2; ++i) {
                ah[i] = *(const bf16x8*)&ash[sw8(wvi * 32 + i * 16 + l15, c)];
                if (!isv) al[i] = *(const bf16x8*)&asl[sw8(wvi * 32 + i * 16 + l15, c)];
            }
            #pragma unroll
            for (int j = 0; j < 4; ++j) {
                bh[j] = *(const bf16x8*)&bsh[sw8(j * 16 + l15, c)];
                if (!isv) bl[j] = *(const bf16x8*)&bsl[sw8(j * 16 + l15, c)];
            }
            #pragma unroll
            for (int i = 0; i < 2; ++i)
                #pragma unroll
                for (int j = 0; j < 4; ++j) {
                    acc[i][j] = MFMA(ah[i], bh[j], acc[i][j]);
                    if (!isv) {
                        acc[i][j] = MFMA(ah[i], bl[j], acc[i][j]);
                        acc[i][j] = MFMA(al[i], bh[j], acc[i][j]);
                    }
                }
        }
    }

    if (isv) {
        #pragma unroll
        for (int j = 0; j < 4; ++j) {
            const int e = j * 16 + l15;
            #pragma unroll
            for (int i = 0; i < 2; ++i) {
                const int nb = n0 + wvi * 32 + i * 16 + quad * 4;
                ushort4 pk;
                pk.x = f2bf(acc[i][j][0]);
                pk.y = f2bf(acc[i][j][1]);
                pk.z = f2bf(acc[i][j][2]);
                pk.w = f2bf(acc[i][j][3]);
                *(ushort4*)&Vt[((size_t)hh * 64 + e) * N + nb] = pk;
            }
        }
    } else {
        const float scale = (sec == 0) ? 0.125f : 1.0f;  // fold 1/sqrt(64) into Q
        unsigned short* Oh = (sec == 0) ? Qh : Kh;
        unsigned short* Ol = (sec == 0) ? Ql : Kl;
        #pragma unroll
        for (int j = 0; j < 4; ++j) {
            const int e = j * 16 + l15;
            #pragma unroll
            for (int i = 0; i < 2; ++i)
                #pragma unroll
                for (int r = 0; r < 4; ++r) {
                    const int n = n0 + wvi * 32 + i * 16 + quad * 4 + r;
                    const float val = acc[i][j][r] * scale;
                    const unsigned short hv = f2bf(val);
                    Oh[((size_t)hh * N + n) * E + e] = hv;
                    Ol[((size_t)hh * N + n) * E + e] = f2bf(val - bf2f(hv));
                }
        }
    }
}

// ---------------------------------------------------------------------------
// K3: flash attention (R5 control, single-bf16 ctx output). grid (32, 16).
// ---------------------------------------------------------------------------
__global__ __launch_bounds__(256, 2) void attn_kernel(
    const unsigned short* __restrict__ Qh, const unsigned short* __restrict__ Ql,
    const unsigned short* __restrict__ Kh, const unsigned short* __restrict__ Kl,
    const unsigned short* __restrict__ Vt,
    unsigned short* __restrict__ Ch)
{
    __shared__ unsigned short ksh[128 * 64], ksl[128 * 64];
    __shared__ unsigned short vts[64 * 128];
    __shared__ unsigned short ps[4 * 16 * 136];
    const int r0 = blockIdx.x * 64, h = blockIdx.y;
    const int t = threadIdx.x, lane = t & 63, wvi = t >> 6, quad = lane >> 4, l15 = lane & 15;

    bf16x8 qfh[2], qfl[2];
    {
        const size_t base = ((size_t)h * N + r0 + wvi * 16 + l15) * E;
        #pragma unroll
        for (int kwi = 0; kwi < 2; ++kwi) {
            qfh[kwi] = *(const bf16x8*)&Qh[base + kwi * 32 + quad * 8];
            qfl[kwi] = *(const bf16x8*)&Ql[base + kwi * 32 + quad * 8];
        }
    }

    f32x4 oacc[4];
    #pragma unroll
    for (int ct = 0; ct < 4; ++ct) oacc[ct] = (f32x4){0.f, 0.f, 0.f, 0.f};
    float mrow[4] = {-1e30f, -1e30f, -1e30f, -1e30f};
    float lrow[4] = {0.f, 0.f, 0.f, 0.f};

    for (int m0 = 0; m0 < N; m0 += 128) {
        __syncthreads();
        #pragma unroll
        for (int p = 0; p < 4; ++p) {
            const int row = p * 32 + wvi * 8 + (lane >> 3);
            const int lc = (lane & 7) ^ (row & 7);
            const int lo = p * 2048 + wvi * 512 + lane * 8;
            const size_t gk = ((size_t)h * N + m0 + row) * E + lc * 8;
            dma16(&Kh[gk], &ksh[lo]);
            dma16(&Kl[gk], &ksl[lo]);
        }
        #pragma unroll
        for (int p = 0; p < 4; ++p) {
            const int row = p * 16 + wvi * 4 + (lane >> 4);
            const int lc = (lane & 15) ^ (row & 7);
            const int lo = p * 2048 + wvi * 512 + lane * 8;
            dma16(&Vt[((size_t)h * 64 + row) * N + m0 + lc * 8], &vts[lo]);
        }
        __syncthreads();

        f32x4 s[8];
        #pragma unroll
        for (int ct = 0; ct < 8; ++ct) s[ct] = (f32x4){0.f, 0.f, 0.f, 0.f};
        #pragma unroll
        for (int kwi = 0; kwi < 2; ++kwi) {
            const int c = kwi * 4 + quad;
            #pragma unroll
            for (int ct = 0; ct < 8; ++ct) {
                const bf16x8 bh = *(const bf16x8*)&ksh[sw8(ct * 16 + l15, c)];
                const bf16x8 bl = *(const bf16x8*)&ksl[sw8(ct * 16 + l15, c)];
                s[ct] = MFMA(qfh[kwi], bh, s[ct]);
                s[ct] = MFMA(qfh[kwi], bl, s[ct]);
                s[ct] = MFMA(qfl[kwi], bh, s[ct]);
            }
        }

        #pragma unroll
        for (int r = 0; r < 4; ++r) {
            float mx = s[0][r];
            #pragma unroll
            for (int ct = 1; ct < 8; ++ct) mx = fmaxf(mx, s[ct][r]);
            mx = fmaxf(mx, __shfl_xor(mx, 1));
            mx = fmaxf(mx, __shfl_xor(mx, 2));
            mx = fmaxf(mx, __shfl_xor(mx, 4));
            mx = fmaxf(mx, __shfl_xor(mx, 8));
            const float mn = fmaxf(mrow[r], mx);
            const float alpha = __expf(mrow[r] - mn);
            mrow[r] = mn;
            float sum = 0.f;
            #pragma unroll
            for (int ct = 0; ct < 8; ++ct) {
                const float p = __expf(s[ct][r] - mn);
                s[ct][r] = p;
                sum += p;
            }
            sum += __shfl_xor(sum, 1);
            sum += __shfl_xor(sum, 2);
            sum += __shfl_xor(sum, 4);
            sum += __shfl_xor(sum, 8);
            lrow[r] = lrow[r] * alpha + sum;
            #pragma unroll
            for (int ct = 0; ct < 4; ++ct) oacc[ct][r] *= alpha;
        }

        #pragma unroll
        for (int ct = 0; ct < 8; ++ct)
            #pragma unroll
            for (int r = 0; r < 4; ++r)
                ps[(wvi * 16 + quad * 4 + r) * 136 + ct * 16 + l15] = f2bf(s[ct][r]);

        #pragma unroll
        for (int kwi = 0; kwi < 4; ++kwi) {
            const bf16x8 pa = *(const bf16x8*)&ps[(wvi * 16 + l15) * 136 + kwi * 32 + quad * 8];
            #pragma unroll
            for (int ct = 0; ct < 4; ++ct) {
                const bf16x8 vb = *(const bf16x8*)&vts[sw16(ct * 16 + l15, kwi * 4 + quad)];
                oacc[ct] = MFMA(pa, vb, oacc[ct]);
            }
        }
    }

    #pragma unroll
    for (int r = 0; r < 4; ++r) {
        const float inv = 1.f / lrow[r];
        const int n = r0 + wvi * 16 + quad * 4 + r;
        #pragma unroll
        for (int ct = 0; ct < 4; ++ct)
            Ch[(size_t)n * D + h * 64 + ct * 16 + l15] = f2bf(oacc[ct][r] * inv);
    }
}

// ---------------------------------------------------------------------------
// K4: out = ctx @ Wo, single-term bf16. grid (32, 16); tile 64x64, BK=64.
// ---------------------------------------------------------------------------
__global__ __launch_bounds__(256, 4) void out_proj_kernel(
    const unsigned short* __restrict__ Chh, const unsigned short* __restrict__ Wh,
    float* __restrict__ out)
{
    __shared__ unsigned short ash[64 * 64], bsh[64 * 64];
    const int n0 = blockIdx.x * 64, c0 = blockIdx.y * 64;
    const int t = threadIdx.x, lane = t & 63, wvi = t >> 6, quad = lane >> 4, l15 = lane & 15;

    f32x4 acc[4];
    #pragma unroll
    for (int j = 0; j < 4; ++j) acc[j] = (f32x4){0.f, 0.f, 0.f, 0.f};

    for (int k0 = 0; k0 < D; k0 += 64) {
        __syncthreads();
        #pragma unroll
        for (int p = 0; p < 2; ++p) {
            const int row = p * 32 + wvi * 8 + (lane >> 3);
            const int lc = (lane & 7) ^ (row & 7);
            const int lo = p * 2048 + wvi * 512 + lane * 8;
            dma16(&Chh[(size_t)(n0 + row) * D + k0 + lc * 8], &ash[lo]);
            dma16(&Wh[(size_t)(c0 + row) * D + k0 + lc * 8], &bsh[lo]);
        }
        __syncthreads();

        #pragma unroll
        for (int kwi = 0; kwi < 2; ++kwi) {
            const int c = kwi * 4 + quad;
            const bf16x8 ah = *(const bf16x8*)&ash[sw8(wvi * 16 + l15, c)];
            #pragma unroll
            for (int j = 0; j < 4; ++j) {
                const bf16x8 bh = *(const bf16x8*)&bsh[sw8(j * 16 + l15, c)];
                acc[j] = MFMA(ah, bh, acc[j]);
            }
        }
    }

    #pragma unroll
    for (int r = 0; r < 4; ++r) {
        const int n = n0 + wvi * 16 + quad * 4 + r;
        #pragma unroll
        for (int j = 0; j < 4; ++j)
            out[(size_t)n * D + c0 + j * 16 + l15] = acc[j][r];
    }
}

// ---------------------------------------------------------------------------
extern "C" void kernel_launch(void* const* d_in, const int* in_sizes, int n_in,
                              void* d_out, int out_size, void* d_ws, size_t ws_size,
                              hipStream_t stream) {
    const float* x  = (const float*)d_in[0];
    const float* qw = (const float*)d_in[1];
    const float* kw = (const float*)d_in[2];
    const float* vw = (const float*)d_in[3];
    const float* ow = (const float*)d_in[4];
    float* out = (float*)d_out;

    unsigned short* ws = (unsigned short*)d_ws;
    const size_t M1 = 1024 * 1024;
    unsigned short* wBh = ws;                 // [2048][1024] = 2M shorts
    unsigned short* wBl = ws + 2 * M1;
    unsigned short* wvt = ws + 4 * M1;        // [1024][1024] = 1M
    unsigned short* woh = ws + 5 * M1;
    unsigned short* xh  = ws + 6 * M1;        // [2048][1024] = 2M
    unsigned short* xl  = ws + 8 * M1;
    unsigned short* Qh  = ws + 10 * M1;       // [h][n][e] = 2M each
    unsigned short* Ql  = ws + 12 * M1;
    unsigned short* Kh  = ws + 14 * M1;
    unsigned short* Kl  = ws + 16 * M1;
    unsigned short* Vt  = ws + 18 * M1;       // [h*64+e][n] = 2M
    unsigned short* Ch  = xh;                 // alias: x dead after qkv

    convert_all_kernel<<<3072, 256, 0, stream>>>(x, qw, kw, vw, ow,
                                                 xh, xl, wBh, wBl, wvt, woh);
    qkv_kernel<<<dim3(16, 48), 256, 0, stream>>>(xh, xl, wBh, wBl, wvt,
                                                 Qh, Ql, Kh, Kl, Vt);
    attn_kernel<<<dim3(32, 16), 256, 0, stream>>>(Qh, Ql, Kh, Kl, Vt, Ch);
    out_proj_kernel<<<dim3(32, 16), 256, 0, stream>>>(Ch, woh, out);
}